// Round 12
// baseline (399.758 us; speedup 1.0000x reference)
//
#include <hip/hip_runtime.h>

typedef unsigned short u16;
typedef unsigned int u32;
typedef __attribute__((ext_vector_type(8))) short short8;
typedef __attribute__((ext_vector_type(8))) __bf16 bf16x8;
typedef __attribute__((ext_vector_type(4))) float f32x4;
typedef __attribute__((ext_vector_type(16))) float f32x16;
typedef __attribute__((ext_vector_type(4))) unsigned short us4;
typedef __attribute__((ext_vector_type(4))) unsigned int u32x4;

#define DEVFN static __device__ __forceinline__

DEVFN u16 f2bf(float f) {
  u32 u = __float_as_uint(f);
  return (u16)((u + 0x7fffu + ((u >> 16) & 1u)) >> 16);  // RNE, finite inputs
}

#if __has_builtin(__builtin_amdgcn_exp2f)
DEVFN float fexp2(float x) { return __builtin_amdgcn_exp2f(x); }
#else
DEVFN float fexp2(float x) { return exp2f(x); }
#endif

DEVFN float fmax3(float a, float b, float c) {  // clang fuses to v_max3_f32
  return fmaxf(fmaxf(a, b), c);
}

// ---- MFMA wrappers: tolerant of short8-typed or bf16x8-typed builtins ----
template <typename T>
DEVFN auto mfma16_imp(T a, T b, f32x4 c, int)
    -> decltype(__builtin_amdgcn_mfma_f32_16x16x32_bf16(a, b, c, 0, 0, 0)) {
  return __builtin_amdgcn_mfma_f32_16x16x32_bf16(a, b, c, 0, 0, 0);
}
template <typename T>
DEVFN f32x4 mfma16_imp(T a, T b, f32x4 c, long) {
  return __builtin_amdgcn_mfma_f32_16x16x32_bf16(
      __builtin_bit_cast(bf16x8, a), __builtin_bit_cast(bf16x8, b), c, 0, 0, 0);
}
DEVFN f32x4 MFMA(short8 a, short8 b, f32x4 c) { return mfma16_imp(a, b, c, 0); }

template <typename T>
DEVFN auto mfma32_imp(T a, T b, f32x16 c, int)
    -> decltype(__builtin_amdgcn_mfma_f32_32x32x16_bf16(a, b, c, 0, 0, 0)) {
  return __builtin_amdgcn_mfma_f32_32x32x16_bf16(a, b, c, 0, 0, 0);
}
template <typename T>
DEVFN f32x16 mfma32_imp(T a, T b, f32x16 c, long) {
  return __builtin_amdgcn_mfma_f32_32x32x16_bf16(
      __builtin_bit_cast(bf16x8, a), __builtin_bit_cast(bf16x8, b), c, 0, 0, 0);
}
DEVFN f32x16 MFMA32(short8 a, short8 b, f32x16 c) { return mfma32_imp(a, b, c, 0); }

// ---- async global->LDS: dest = uniform base + lane*16 ----
DEVFN void gload_lds16(const u16* g, u16* l) {
  __builtin_amdgcn_global_load_lds(
      (__attribute__((address_space(1))) void*)g,
      (__attribute__((address_space(3))) void*)l, 16, 0, 0);
}

DEVFN u32 cvtpk_bf16(float lo, float hi) {
  u32 w;
  asm("v_cvt_pk_bf16_f32 %0, %1, %2" : "=v"(w) : "v"(lo), "v"(hi));
  return w;
}

// ================= fused f32 -> bf16 conversion (one launch) =============
__global__ void __launch_bounds__(256) cvt_all(
    const float* __restrict__ x, u16* __restrict__ xo,
    const float* __restrict__ w1, u16* __restrict__ w1o,
    const float* __restrict__ w2, u16* __restrict__ w2o) {
  int bid = blockIdx.x;
  const float* in;
  u16* out;
  int i;
  if (bid < 4096) {
    in = x; out = xo; i = bid * 256 + threadIdx.x;
  } else if (bid < 7168) {
    in = w1; out = w1o; i = (bid - 4096) * 256 + threadIdx.x;
  } else {
    in = w2; out = w2o; i = (bid - 7168) * 256 + threadIdx.x;
  }
  f32x4 v = ((const f32x4*)in)[i];
  us4 o;
  o[0] = f2bf(v[0]); o[1] = f2bf(v[1]); o[2] = f2bf(v[2]); o[3] = f2bf(v[3]);
  ((us4*)out)[i] = o;
}

// ====== GEMM tile body (BK=32): C[bm:+128, bn:+BN] = A @ B^T =============
// Used by the output projection (BN=64 -> 512 blocks, 2/CU).
template <int F32OUT, int BN>
DEVFN void gemm_tile(const u16* __restrict__ A, const u16* __restrict__ Bm,
                     u16* __restrict__ Cbf, float* __restrict__ Cf,
                     const float* __restrict__ bias, int N, int K, int bm,
                     int bn, u16* As, u16* Bs) {
  const int tid = threadIdx.x;
  const int wave = tid >> 6, lane = tid & 63;
  const int wr = (wave >> 1) * 64, wc = (wave & 1) * (BN / 2);
  const int srow = lane >> 2, scol = (lane & 3) * 8;
  const int fr = lane & 15, fk = (lane >> 4) * 8;
  const int NB = BN / 64;  // B-stage iters per wave
  const int NI = BN / 32;  // n-frags per wave

  f32x4 acc[4][NI] = {};

  for (int k0 = 0; k0 < K; k0 += 32) {
    __syncthreads();
#pragma unroll
    for (int t = 0; t < 2; ++t) {
      int rr = (wave * 2 + t) * 16 + srow;
      gload_lds16(A + (size_t)(bm + rr) * K + k0 + scol, As + (wave * 2 + t) * 512);
    }
#pragma unroll
    for (int t = 0; t < NB; ++t) {
      int rr = (wave * NB + t) * 16 + srow;
      gload_lds16(Bm + (size_t)(bn + rr) * K + k0 + scol, Bs + (wave * NB + t) * 512);
    }
    __syncthreads();
    short8 af[4], bf[NI];
#pragma unroll
    for (int i = 0; i < 4; ++i)
      af[i] = *(const short8*)(As + (wr + i * 16 + fr) * 32 + fk);
#pragma unroll
    for (int i = 0; i < NI; ++i)
      bf[i] = *(const short8*)(Bs + (wc + i * 16 + fr) * 32 + fk);
#pragma unroll
    for (int mi = 0; mi < 4; ++mi)
#pragma unroll
      for (int ni = 0; ni < NI; ++ni)
        acc[mi][ni] = MFMA(af[mi], bf[ni], acc[mi][ni]);
  }

  const int orow = (lane >> 4) * 4, ocol = lane & 15;
#pragma unroll
  for (int mi = 0; mi < 4; ++mi)
#pragma unroll
    for (int ni = 0; ni < NI; ++ni)
#pragma unroll
      for (int r = 0; r < 4; ++r) {
        size_t row = (size_t)(bm + wr + mi * 16 + orow + r);
        size_t col = (size_t)(bn + wc + ni * 16 + ocol);
        if (F32OUT)
          Cf[row * N + col] = acc[mi][ni][r] + bias[col];
        else
          Cbf[row * N + col] = f2bf(acc[mi][ni][r]);
      }
}

// ====== output projection: 128x64 tiles, 512 blocks (2/CU) + T1 swizzle ===
__global__ void __launch_bounds__(256) gemm_proj(
    const u16* __restrict__ A, const u16* __restrict__ Bm,
    float* __restrict__ Cf, const float* __restrict__ bias, int M, int N,
    int K) {
  __shared__ u16 As[128 * 32];
  __shared__ u16 Bs[64 * 32];
  const int B = blockIdx.x;
  const int L = (B & 7) * 64 + (B >> 3);
  gemm_tile<1, 64>(A, Bm, nullptr, Cf, bias, N, K, (L >> 4) * 128,
                   (L & 15) * 64, As, Bs);
}

// ====== GEMM tile body, BK=64 (R8: neutral vs BK=32, kept) ================
DEVFN void gemm_tile64(const u16* __restrict__ A, const u16* __restrict__ Bm,
                       u16* __restrict__ C, int N, int K, int bm, int bn,
                       u16* As, u16* Bs) {
  const int tid = threadIdx.x;
  const int wave = tid >> 6, lane = tid & 63;
  const int wr = (wave >> 1) * 64, wc = (wave & 1) * 64;
  const int rowl = lane >> 3;                     // row within 8-row group
  const int scol = ((lane & 7) ^ rowl) * 8;       // pre-swizzled src chunk
  const int fr = lane & 15, fkc = lane >> 4;      // frag row / logical chunk

  f32x4 acc[4][4] = {};

  for (int k0 = 0; k0 < K; k0 += 64) {
    __syncthreads();
#pragma unroll
    for (int t = 0; t < 4; ++t) {
      int gA = wave * 4 + t;  // 16 groups x 8 rows = 128 rows
      int row = gA * 8 + rowl;
      gload_lds16(A + (size_t)(bm + row) * K + k0 + scol, As + gA * 512);
      gload_lds16(Bm + (size_t)(bn + row) * K + k0 + scol, Bs + gA * 512);
    }
    __syncthreads();
#pragma unroll
    for (int ks = 0; ks < 2; ++ks) {
      short8 af[4], bf[4];
#pragma unroll
      for (int i = 0; i < 4; ++i) {
        int ra = wr + i * 16 + fr, rb = wc + i * 16 + fr;
        int lc = fkc + ks * 4;
        af[i] = *(const short8*)(As + ra * 64 + ((lc ^ (ra & 7)) * 8));
        bf[i] = *(const short8*)(Bs + rb * 64 + ((lc ^ (rb & 7)) * 8));
      }
#pragma unroll
      for (int mi = 0; mi < 4; ++mi)
#pragma unroll
        for (int ni = 0; ni < 4; ++ni)
          acc[mi][ni] = MFMA(af[mi], bf[ni], acc[mi][ni]);
    }
  }

  const int orow = (lane >> 4) * 4, ocol = lane & 15;
#pragma unroll
  for (int mi = 0; mi < 4; ++mi)
#pragma unroll
    for (int ni = 0; ni < 4; ++ni)
#pragma unroll
      for (int r = 0; r < 4; ++r) {
        size_t row = (size_t)(bm + wr + mi * 16 + orow + r);
        size_t col = (size_t)(bn + wc + ni * 16 + ocol);
        C[row * N + col] = f2bf(acc[mi][ni][r]);
      }
}

// ====== fused projection + T1 XCD swizzle =================================
__global__ void __launch_bounds__(256) fused_qkv_gemm(
    const u16* __restrict__ x, const u16* __restrict__ wqkv,
    u16* __restrict__ qk, u16* __restrict__ vt) {
  __shared__ u16 As[128 * 64];
  __shared__ u16 Bs[128 * 64];
  const int B = blockIdx.x;
  const int L = (B & 7) * 96 + (B >> 3);
  if (L < 512) {
    gemm_tile64(x, wqkv, qk, 2048, 1024, (L >> 4) * 128, (L & 15) * 128,
                As, Bs);
  } else {
    int j = L - 512;
    gemm_tile64(wqkv + (size_t)2048 * 1024, x, vt, 4096, 1024, (j & 7) * 128,
                (j >> 3) * 128, As, Bs);
  }
}

// ================= Flash attention v6: 4-way KV split, 8 waves/SIMD =======
// qk: [4096, 2048] bf16 (Q|K). vT: [1024, 4096] bf16 (vfeat, token).
// 1D grid 512 blocks x 1024 thr (16 waves). g = wave>>2 owns kv
// [g*512, g*512+512) (8 tiles); gw = wave&3 owns q-rows gw*32..+32.
// Single-buffered K/V (4 groups x 16KB = 64KB) -> 2 blocks/CU co-reside ->
// 32 waves/CU = 8 waves/SIMD (R12 rationale: R11 calibration shows ~40%
// SIMD-issue stall at 4 waves/SIMD; occupancy is the remaining lever).
// __launch_bounds__(1024,8) pins VGPR<=64 (R11 kernel compiles at exactly 64
// with the same inner loop; R2 lesson: only force a cap the state fits).
// Single-buffer serialization is covered by TLP (m114; R1: dbuf null).
// Combine: 3-round pairwise merge (g1->g0, g3->g2, g2->g0) via LDS overlay.
__global__ void __launch_bounds__(1024, 8) attn_kernel(
    const u16* __restrict__ qk, const u16* __restrict__ vT,
    u16* __restrict__ attn_out) {
  // 64KB: K(g) at g*4096 u16, V(g) at 16384 + g*4096 u16 (single-buffered)
  __shared__ u16 SM[32768];

  const int tid = threadIdx.x;
  const int wave = tid >> 6, lane = tid & 63;
  const int g = wave >> 2, gw = wave & 3;  // kv-group, q-sub
  const int q5 = lane & 31, hi = lane >> 5;

  // ---- T1 XCD-aware decode (R9 verified): qb fastest, (h,b) per XCD ----
  const int B = blockIdx.x;                 // 0..511
  const int L = (B & 7) * 64 + (B >> 3);    // bijective swizzle
  const int qb = L & 15, hb = L >> 4;
  const int h = hb & 15, b = hb >> 4;

  const size_t tok0 = (size_t)b * 2048;
  const float SCALE = 0.18033688011112042f;  // 0.125 * log2(e)

  u16* const Kg = SM + g * 4096;
  u16* const Vg = SM + 16384 + g * 4096;
  const int kvoff = g * 512;

  // Q B-frags: lane q5 holds Q[q][ks*16 + hi*8 + j]
  const size_t qrow = tok0 + qb * 128 + gw * 32 + q5;
  const u16* qp = qk + qrow * 2048 + h * 64 + hi * 8;
  short8 qf[4];
#pragma unroll
  for (int ks = 0; ks < 4; ++ks) qf[ks] = *(const short8*)(qp + ks * 16);

  const u16* kbase = qk + tok0 * 2048 + 1024 + h * 64;  // + kv*2048
  const u16* vtb = vT + (size_t)h * 64 * 4096 + tok0;   // + d*4096 + kv

  // Static per-lane staging geometry (per group: 4 waves cover 8 row-groups)
  const int rowl = lane >> 3;
  const int k_srcoff = ((lane & 7) ^ rowl) * 8;  // K swizzle key = (row&7)

  float m_run = -1e30f, l_run = 0.f;  // l_run: per-half partial (R11)
  f32x16 o0 = {}, o1 = {};

#define STAGE(kv0)                                                             \
  {                                                                            \
    _Pragma("unroll") for (int c = 0; c < 2; ++c) {                            \
      int rw = c * 4 + gw;                                                     \
      int row = rw * 8 + rowl;                                                 \
      gload_lds16(kbase + (size_t)((kv0) + row) * 2048 + k_srcoff,             \
                  Kg + rw * 512);                                              \
      int vso = (((lane & 7) ^ rowl ^ rw) * 8);  /* key = (d&7)^((d>>3)&7) */  \
      gload_lds16(vtb + (size_t)row * 4096 + (kv0) + vso, Vg + rw * 512);      \
    }                                                                          \
  }

  for (int t = 0; t < 8; ++t) {
    STAGE(kvoff + t * 64);
    __syncthreads();  // stage visible (implicit vmcnt drain) before reads

    // ---- S^T = K . Q^T : 2 tiles (kv 0-31 / 32-63), 4 k-steps ----
    f32x16 s0 = {}, s1 = {};
    __builtin_amdgcn_s_setprio(1);
#pragma unroll
    for (int ks = 0; ks < 4; ++ks) {
      int ch = ((ks * 2 + hi) ^ (q5 & 7)) * 8;
      short8 k0 = *(const short8*)(Kg + q5 * 64 + ch);
      short8 k1 = *(const short8*)(Kg + (32 + q5) * 64 + ch);
      s0 = MFMA32(k0, qf[ks], s0);
      s1 = MFMA32(k1, qf[ks], s1);
    }
    __builtin_amdgcn_s_setprio(0);

    // ---- online softmax, per-lane scalars (lane owns q = q5) ----
    // max3 tree: 32 values in 15 v_max3 + 1 v_max (R11)
    float m0 = fmax3(s0[0], s0[1], s0[2]);
    float m1 = fmax3(s0[3], s0[4], s0[5]);
    float m2 = fmax3(s0[6], s0[7], s0[8]);
    float m3 = fmax3(s0[9], s0[10], s0[11]);
    float m4 = fmax3(s0[12], s0[13], s0[14]);
    float m5 = fmax3(s0[15], s1[0], s1[1]);
    float m6 = fmax3(s1[2], s1[3], s1[4]);
    float m7 = fmax3(s1[5], s1[6], s1[7]);
    float m8 = fmax3(s1[8], s1[9], s1[10]);
    float m9 = fmax3(s1[11], s1[12], s1[13]);
    float ma = fmaxf(s1[14], s1[15]);
    float n0 = fmax3(m0, m1, m2);
    float n1 = fmax3(m3, m4, m5);
    float n2 = fmax3(m6, m7, m8);
    float n3 = fmax3(m9, ma, n0);
    float pmax = fmax3(n1, n2, n3);
    pmax = fmaxf(pmax, __shfl_xor(pmax, 32, 64));
    float mraw = pmax * SCALE;

    if (__any(mraw > m_run + 8.f)) {  // T13 defer-max, wave-uniform
      float mn = fmaxf(m_run, mraw);
      float alpha = fexp2(m_run - mn);
#pragma unroll
      for (int i = 0; i < 16; ++i) { o0[i] *= alpha; o1[i] *= alpha; }
      l_run *= alpha;
      m_run = mn;
    }

    float p0[16], p1[16];
    float rs = 0.f;
#pragma unroll
    for (int i = 0; i < 16; ++i) {
      p0[i] = fexp2(fmaf(s0[i], SCALE, -m_run));
      p1[i] = fexp2(fmaf(s1[i], SCALE, -m_run));
      rs += p0[i] + p1[i];
    }
    l_run += rs;  // own-half partial; cross-half deferred (R11)

    // ---- P^T -> PV B-frags in-register (cvt_pk + permlane32_swap) ----
    u32 w0[4][2], w1[4][2];
#pragma unroll
    for (int a = 0; a < 4; ++a) {
      w0[a][0] = cvtpk_bf16(p0[4 * a], p0[4 * a + 1]);
      w0[a][1] = cvtpk_bf16(p0[4 * a + 2], p0[4 * a + 3]);
      w1[a][0] = cvtpk_bf16(p1[4 * a], p1[4 * a + 1]);
      w1[a][1] = cvtpk_bf16(p1[4 * a + 2], p1[4 * a + 3]);
    }
    short8 pb[4];
#pragma unroll
    for (int ks = 0; ks < 4; ++ks) {
      int e = ks & 1;
      u32 x0 = (ks < 2) ? w0[2 * e][0] : w1[2 * e][0];
      u32 y0 = (ks < 2) ? w0[2 * e + 1][0] : w1[2 * e + 1][0];
      u32 x1 = (ks < 2) ? w0[2 * e][1] : w1[2 * e][1];
      u32 y1 = (ks < 2) ? w0[2 * e + 1][1] : w1[2 * e + 1][1];
      asm("v_permlane32_swap_b32 %0, %1" : "+v"(x0), "+v"(y0));
      asm("v_permlane32_swap_b32 %0, %1" : "+v"(x1), "+v"(y1));
      u32x4 tt = {x0, x1, y0, y1};  // words j={0,1},{2,3},{4,5},{6,7}
      pb[ks] = __builtin_bit_cast(short8, tt);
    }

    // ---- O^T += V^T . P^T ----
    __builtin_amdgcn_s_setprio(1);
#pragma unroll
    for (int ks = 0; ks < 4; ++ks) {
      int ch0 = ((ks * 2 + hi) ^ (q5 & 7) ^ ((q5 >> 3) & 7)) * 8;
      int ch1 = ch0 ^ (4 * 8);  // row 32+q5: (d>>3) flips bit 2
      short8 v0 = *(const short8*)(Vg + q5 * 64 + ch0);
      short8 v1 = *(const short8*)(Vg + (32 + q5) * 64 + ch1);
      o0 = MFMA32(v0, pb[ks], o0);
      o1 = MFMA32(v1, pb[ks], o1);
    }
    __builtin_amdgcn_s_setprio(0);

    __syncthreads();  // all group reads done before next-tile overwrite
  }
#undef STAGE

  // deferred cross-half l reduction (R11)
  l_run += __shfl_xor(l_run, 32, 64);

  // ---- 3-round flash-combine: g1->g0, g3->g2, g2->g0 ----
  // overlay (K/V dead): per gw slot = M[64] | L[64] | O[32][64] = 8704B;
  // 4 slots = 34816B <= 64KB. f32 throughout (precision).
  float* const base = (float*)SM + gw * 2176;
  auto writeP = [&]() {
    base[lane] = m_run;
    base[64 + lane] = l_run;
#pragma unroll
    for (int i = 0; i < 16; ++i) {
      base[128 + i * 64 + lane] = o0[i];
      base[128 + (16 + i) * 64 + lane] = o1[i];
    }
  };
  auto mergeP = [&]() {
    float mo = base[lane], lo_ = base[64 + lane];
    float M = fmaxf(m_run, mo);
    float wa = fexp2(m_run - M), wb = fexp2(mo - M);
    l_run = wa * l_run + wb * lo_;
#pragma unroll
    for (int i = 0; i < 16; ++i) {
      o0[i] = wa * o0[i] + wb * base[128 + i * 64 + lane];
      o1[i] = wa * o1[i] + wb * base[128 + (16 + i) * 64 + lane];
    }
    m_run = M;
  };

  if (g == 1) writeP();
  __syncthreads();
  if (g == 0) mergeP();
  __syncthreads();  // g0 reads complete before g3 overwrites
  if (g == 3) writeP();
  __syncthreads();
  if (g == 2) mergeP();
  __syncthreads();  // g2 reads complete before g2 re-writes
  if (g == 2) writeP();
  __syncthreads();
  if (g == 0) {
    mergeP();
    float inv = 1.f / l_run;
    // epilogue: O^T[d][q], lane q5; d = (reg&3)+8*(reg>>2)+4*hi+32*dt
#pragma unroll
    for (int dt = 0; dt < 2; ++dt)
#pragma unroll
      for (int gq = 0; gq < 4; ++gq) {
        us4 st;
#pragma unroll
        for (int c2 = 0; c2 < 4; ++c2) {
          int i = 4 * gq + c2;
          float val = (dt == 0 ? o0[i] : o1[i]) * inv;
          st[c2] = f2bf(val);
        }
        int col = h * 64 + dt * 32 + 8 * gq + 4 * hi;
        *(us4*)(attn_out + qrow * 1024 + col) = st;
      }
  }
}

// ================= launcher =================
extern "C" void kernel_launch(void* const* d_in, const int* in_sizes, int n_in,
                              void* d_out, int out_size, void* d_ws, size_t ws_size,
                              hipStream_t stream) {
  const float* x = (const float*)d_in[0];
  const float* Wqkv = (const float*)d_in[1];
  const float* Wproj = (const float*)d_in[2];
  const float* bproj = (const float*)d_in[3];
  float* out = (float*)d_out;

  char* ws = (char*)d_ws;
  u16* x_bf     = (u16*)(ws);                 //  8 MB  [4096,1024]
  u16* wqkv_bf  = (u16*)(ws + 8388608);       //  6 MB  [3072,1024]
  u16* wproj_bf = (u16*)(ws + 14680064);      //  2 MB  [1024,1024]
  u16* qk_bf    = (u16*)(ws + 16777216);      // 16 MB  [4096,2048] (Q|K)
  u16* vt_bf    = (u16*)(ws + 33554432);      //  8 MB  [1024,4096] V^T
  u16* attn_bf  = (u16*)(ws + 41943040);      //  8 MB  [4096,1024]

  cvt_all<<<8192, 256, 0, stream>>>(x, x_bf, Wqkv, wqkv_bf, Wproj, wproj_bf);

  fused_qkv_gemm<<<768, 256, 0, stream>>>(x_bf, wqkv_bf, qk_bf, vt_bf);

  attn_kernel<<<512, 1024, 0, stream>>>(qk_bf, vt_bf, attn_bf);

  gemm_proj<<<512, 256, 0, stream>>>(attn_bf, wproj_bf, out, bproj,
                                     4096, 1024, 1024);
}

// Round 13
// 117.078 us; speedup vs baseline: 3.4145x; 3.4145x over previous
//
#include <hip/hip_runtime.h>

typedef unsigned short u16;
typedef unsigned int u32;
typedef __attribute__((ext_vector_type(8))) short short8;
typedef __attribute__((ext_vector_type(8))) __bf16 bf16x8;
typedef __attribute__((ext_vector_type(4))) float f32x4;
typedef __attribute__((ext_vector_type(16))) float f32x16;
typedef __attribute__((ext_vector_type(4))) unsigned short us4;
typedef __attribute__((ext_vector_type(4))) unsigned int u32x4;

#define DEVFN static __device__ __forceinline__

DEVFN u16 f2bf(float f) {
  u32 u = __float_as_uint(f);
  return (u16)((u + 0x7fffu + ((u >> 16) & 1u)) >> 16);  // RNE, finite inputs
}

#if __has_builtin(__builtin_amdgcn_exp2f)
DEVFN float fexp2(float x) { return __builtin_amdgcn_exp2f(x); }
#else
DEVFN float fexp2(float x) { return exp2f(x); }
#endif

DEVFN float fmax3(float a, float b, float c) {  // clang fuses to v_max3_f32
  return fmaxf(fmaxf(a, b), c);
}

// ---- MFMA wrappers: tolerant of short8-typed or bf16x8-typed builtins ----
template <typename T>
DEVFN auto mfma16_imp(T a, T b, f32x4 c, int)
    -> decltype(__builtin_amdgcn_mfma_f32_16x16x32_bf16(a, b, c, 0, 0, 0)) {
  return __builtin_amdgcn_mfma_f32_16x16x32_bf16(a, b, c, 0, 0, 0);
}
template <typename T>
DEVFN f32x4 mfma16_imp(T a, T b, f32x4 c, long) {
  return __builtin_amdgcn_mfma_f32_16x16x32_bf16(
      __builtin_bit_cast(bf16x8, a), __builtin_bit_cast(bf16x8, b), c, 0, 0, 0);
}
DEVFN f32x4 MFMA(short8 a, short8 b, f32x4 c) { return mfma16_imp(a, b, c, 0); }

template <typename T>
DEVFN auto mfma32_imp(T a, T b, f32x16 c, int)
    -> decltype(__builtin_amdgcn_mfma_f32_32x32x16_bf16(a, b, c, 0, 0, 0)) {
  return __builtin_amdgcn_mfma_f32_32x32x16_bf16(a, b, c, 0, 0, 0);
}
template <typename T>
DEVFN f32x16 mfma32_imp(T a, T b, f32x16 c, long) {
  return __builtin_amdgcn_mfma_f32_32x32x16_bf16(
      __builtin_bit_cast(bf16x8, a), __builtin_bit_cast(bf16x8, b), c, 0, 0, 0);
}
DEVFN f32x16 MFMA32(short8 a, short8 b, f32x16 c) { return mfma32_imp(a, b, c, 0); }

// ---- async global->LDS: dest = uniform base + lane*16 ----
DEVFN void gload_lds16(const u16* g, u16* l) {
  __builtin_amdgcn_global_load_lds(
      (__attribute__((address_space(1))) void*)g,
      (__attribute__((address_space(3))) void*)l, 16, 0, 0);
}

DEVFN u32 cvtpk_bf16(float lo, float hi) {
  u32 w;
  asm("v_cvt_pk_bf16_f32 %0, %1, %2" : "=v"(w) : "v"(lo), "v"(hi));
  return w;
}

// ================= fused f32 -> bf16 conversion (one launch) =============
__global__ void __launch_bounds__(256) cvt_all(
    const float* __restrict__ x, u16* __restrict__ xo,
    const float* __restrict__ w1, u16* __restrict__ w1o,
    const float* __restrict__ w2, u16* __restrict__ w2o) {
  int bid = blockIdx.x;
  const float* in;
  u16* out;
  int i;
  if (bid < 4096) {
    in = x; out = xo; i = bid * 256 + threadIdx.x;
  } else if (bid < 7168) {
    in = w1; out = w1o; i = (bid - 4096) * 256 + threadIdx.x;
  } else {
    in = w2; out = w2o; i = (bid - 7168) * 256 + threadIdx.x;
  }
  f32x4 v = ((const f32x4*)in)[i];
  us4 o;
  o[0] = f2bf(v[0]); o[1] = f2bf(v[1]); o[2] = f2bf(v[2]); o[3] = f2bf(v[3]);
  ((us4*)out)[i] = o;
}

// ====== GEMM tile body (BK=32): C[bm:+128, bn:+BN] = A @ B^T =============
// Used by the output projection (BN=64 -> 512 blocks, 2/CU).
template <int F32OUT, int BN>
DEVFN void gemm_tile(const u16* __restrict__ A, const u16* __restrict__ Bm,
                     u16* __restrict__ Cbf, float* __restrict__ Cf,
                     const float* __restrict__ bias, int N, int K, int bm,
                     int bn, u16* As, u16* Bs) {
  const int tid = threadIdx.x;
  const int wave = tid >> 6, lane = tid & 63;
  const int wr = (wave >> 1) * 64, wc = (wave & 1) * (BN / 2);
  const int srow = lane >> 2, scol = (lane & 3) * 8;
  const int fr = lane & 15, fk = (lane >> 4) * 8;
  const int NB = BN / 64;  // B-stage iters per wave
  const int NI = BN / 32;  // n-frags per wave

  f32x4 acc[4][NI] = {};

  for (int k0 = 0; k0 < K; k0 += 32) {
    __syncthreads();
#pragma unroll
    for (int t = 0; t < 2; ++t) {
      int rr = (wave * 2 + t) * 16 + srow;
      gload_lds16(A + (size_t)(bm + rr) * K + k0 + scol, As + (wave * 2 + t) * 512);
    }
#pragma unroll
    for (int t = 0; t < NB; ++t) {
      int rr = (wave * NB + t) * 16 + srow;
      gload_lds16(Bm + (size_t)(bn + rr) * K + k0 + scol, Bs + (wave * NB + t) * 512);
    }
    __syncthreads();
    short8 af[4], bf[NI];
#pragma unroll
    for (int i = 0; i < 4; ++i)
      af[i] = *(const short8*)(As + (wr + i * 16 + fr) * 32 + fk);
#pragma unroll
    for (int i = 0; i < NI; ++i)
      bf[i] = *(const short8*)(Bs + (wc + i * 16 + fr) * 32 + fk);
#pragma unroll
    for (int mi = 0; mi < 4; ++mi)
#pragma unroll
      for (int ni = 0; ni < NI; ++ni)
        acc[mi][ni] = MFMA(af[mi], bf[ni], acc[mi][ni]);
  }

  const int orow = (lane >> 4) * 4, ocol = lane & 15;
#pragma unroll
  for (int mi = 0; mi < 4; ++mi)
#pragma unroll
    for (int ni = 0; ni < NI; ++ni)
#pragma unroll
      for (int r = 0; r < 4; ++r) {
        size_t row = (size_t)(bm + wr + mi * 16 + orow + r);
        size_t col = (size_t)(bn + wc + ni * 16 + ocol);
        if (F32OUT)
          Cf[row * N + col] = acc[mi][ni][r] + bias[col];
        else
          Cbf[row * N + col] = f2bf(acc[mi][ni][r]);
      }
}

// ====== output projection: 128x64 tiles, 512 blocks (2/CU) + T1 swizzle ===
__global__ void __launch_bounds__(256) gemm_proj(
    const u16* __restrict__ A, const u16* __restrict__ Bm,
    float* __restrict__ Cf, const float* __restrict__ bias, int M, int N,
    int K) {
  __shared__ u16 As[128 * 32];
  __shared__ u16 Bs[64 * 32];
  const int B = blockIdx.x;
  const int L = (B & 7) * 64 + (B >> 3);
  gemm_tile<1, 64>(A, Bm, nullptr, Cf, bias, N, K, (L >> 4) * 128,
                   (L & 15) * 64, As, Bs);
}

// ====== GEMM tile body, BK=64 (R8: neutral vs BK=32, kept) ================
DEVFN void gemm_tile64(const u16* __restrict__ A, const u16* __restrict__ Bm,
                       u16* __restrict__ C, int N, int K, int bm, int bn,
                       u16* As, u16* Bs) {
  const int tid = threadIdx.x;
  const int wave = tid >> 6, lane = tid & 63;
  const int wr = (wave >> 1) * 64, wc = (wave & 1) * 64;
  const int rowl = lane >> 3;                     // row within 8-row group
  const int scol = ((lane & 7) ^ rowl) * 8;       // pre-swizzled src chunk
  const int fr = lane & 15, fkc = lane >> 4;      // frag row / logical chunk

  f32x4 acc[4][4] = {};

  for (int k0 = 0; k0 < K; k0 += 64) {
    __syncthreads();
#pragma unroll
    for (int t = 0; t < 4; ++t) {
      int gA = wave * 4 + t;  // 16 groups x 8 rows = 128 rows
      int row = gA * 8 + rowl;
      gload_lds16(A + (size_t)(bm + row) * K + k0 + scol, As + gA * 512);
      gload_lds16(Bm + (size_t)(bn + row) * K + k0 + scol, Bs + gA * 512);
    }
    __syncthreads();
#pragma unroll
    for (int ks = 0; ks < 2; ++ks) {
      short8 af[4], bf[4];
#pragma unroll
      for (int i = 0; i < 4; ++i) {
        int ra = wr + i * 16 + fr, rb = wc + i * 16 + fr;
        int lc = fkc + ks * 4;
        af[i] = *(const short8*)(As + ra * 64 + ((lc ^ (ra & 7)) * 8));
        bf[i] = *(const short8*)(Bs + rb * 64 + ((lc ^ (rb & 7)) * 8));
      }
#pragma unroll
      for (int mi = 0; mi < 4; ++mi)
#pragma unroll
        for (int ni = 0; ni < 4; ++ni)
          acc[mi][ni] = MFMA(af[mi], bf[ni], acc[mi][ni]);
    }
  }

  const int orow = (lane >> 4) * 4, ocol = lane & 15;
#pragma unroll
  for (int mi = 0; mi < 4; ++mi)
#pragma unroll
    for (int ni = 0; ni < 4; ++ni)
#pragma unroll
      for (int r = 0; r < 4; ++r) {
        size_t row = (size_t)(bm + wr + mi * 16 + orow + r);
        size_t col = (size_t)(bn + wc + ni * 16 + ocol);
        C[row * N + col] = f2bf(acc[mi][ni][r]);
      }
}

// ====== fused projection + T1 XCD swizzle =================================
__global__ void __launch_bounds__(256) fused_qkv_gemm(
    const u16* __restrict__ x, const u16* __restrict__ wqkv,
    u16* __restrict__ qk, u16* __restrict__ vt) {
  __shared__ u16 As[128 * 64];
  __shared__ u16 Bs[128 * 64];
  const int B = blockIdx.x;
  const int L = (B & 7) * 96 + (B >> 3);
  if (L < 512) {
    gemm_tile64(x, wqkv, qk, 2048, 1024, (L >> 4) * 128, (L & 15) * 128,
                As, Bs);
  } else {
    int j = L - 512;
    gemm_tile64(wqkv + (size_t)2048 * 1024, x, vt, 4096, 1024, (j & 7) * 128,
                (j >> 3) * 128, As, Bs);
  }
}

// ================= Flash attention v5.1 (R11 verified best: 53.5us) =======
// qk: [4096, 2048] bf16 (Q|K). vT: [1024, 4096] bf16 (vfeat, token).
// 1D grid 512 blocks x 512 thr (8 waves), in-block KV-split x2, double-buf.
// Occupancy NOTE (R12 lesson): live state = 64 VGPR + 64 AGPR = 128 regs in
// the unified file -> HARD cap 4 waves/SIMD (512/128). This config (2 blocks
// x 8 waves/CU) IS the optimum; forcing more via launch_bounds min-waves
// spills catastrophically (R12: WRITE_SIZE 8MB -> 805MB, 400us).
// T1 XCD swizzle (R9: FETCH 69.7->12.3MB). R11 VALU cuts: deferred cross-half
// l-reduction (16 shfls -> 1), v_max3 pmax tree.
// SQ_LDS_BANK_CONFLICT 2.1M = structural b128 2-way (free, m136) — ignore.
__global__ void __launch_bounds__(512) attn_kernel(const u16* __restrict__ qk,
                                                   const u16* __restrict__ vT,
                                                   u16* __restrict__ attn_out) {
  // 64KB flat: K(g,buf) at (g*2+buf)*4096, V(g,buf) at 16384+(g*2+buf)*4096
  __shared__ u16 SM[32768];

  const int tid = threadIdx.x;
  const int wave = tid >> 6, lane = tid & 63;
  const int g = wave >> 2, gw = wave & 3;  // kv-group, wave-in-group
  const int q5 = lane & 31, hi = lane >> 5;

  // ---- T1 XCD-aware decode: qb fastest in L, (h,b) chunked per XCD ----
  const int B = blockIdx.x;                 // 0..511
  const int L = (B & 7) * 64 + (B >> 3);    // bijective swizzle
  const int qb = L & 15, hb = L >> 4;
  const int h = hb & 15, b = hb >> 4;

  const size_t tok0 = (size_t)b * 2048;
  const float SCALE = 0.18033688011112042f;  // 0.125 * log2(e)

  u16* const Kg = SM + g * 2 * 4096;          // + buf*4096
  u16* const Vg = SM + 16384 + g * 2 * 4096;  // + buf*4096
  const int kvoff = g * 1024;

  // Q B-frags: lane q5 holds Q[q][ks*16 + hi*8 + j]
  const size_t qrow = tok0 + qb * 128 + gw * 32 + q5;
  const u16* qp = qk + qrow * 2048 + h * 64 + hi * 8;
  short8 qf[4];
#pragma unroll
  for (int ks = 0; ks < 4; ++ks) qf[ks] = *(const short8*)(qp + ks * 16);

  const u16* kbase = qk + tok0 * 2048 + 1024 + h * 64;  // + kv*2048
  const u16* vtb = vT + (size_t)h * 64 * 4096 + tok0;   // + d*4096 + kv

  // Static per-lane staging geometry (per group: 4 waves cover 8 row-groups)
  const int rowl = lane >> 3;
  const int k_srcoff = ((lane & 7) ^ rowl) * 8;  // K swizzle key = (row&7)

  float m_run = -1e30f, l_run = 0.f;  // l_run: PER-HALF partial (R11)
  f32x16 o0 = {}, o1 = {};

#define STAGE(kv0, buf)                                                        \
  {                                                                            \
    _Pragma("unroll") for (int c = 0; c < 2; ++c) {                            \
      int rw = c * 4 + gw;                                                     \
      int row = rw * 8 + rowl;                                                 \
      gload_lds16(kbase + (size_t)((kv0) + row) * 2048 + k_srcoff,             \
                  Kg + (buf) * 4096 + rw * 512);                               \
      int vso = (((lane & 7) ^ rowl ^ rw) * 8);  /* key = (d&7)^((d>>3)&7) */  \
      gload_lds16(vtb + (size_t)row * 4096 + (kv0) + vso,                      \
                  Vg + (buf) * 4096 + rw * 512);                               \
    }                                                                          \
  }

  STAGE(kvoff, 0);
  __syncthreads();

  for (int t = 0; t < 16; ++t) {
    const int cur = t & 1, nxt = cur ^ 1;
    if (t < 15) STAGE(kvoff + (t + 1) * 64, nxt);  // in flight across compute

    // ---- S^T = K . Q^T : 2 tiles (kv 0-31 / 32-63), 4 k-steps ----
    const u16* Kc = Kg + cur * 4096;
    f32x16 s0 = {}, s1 = {};
    __builtin_amdgcn_s_setprio(1);
#pragma unroll
    for (int ks = 0; ks < 4; ++ks) {
      int ch = ((ks * 2 + hi) ^ (q5 & 7)) * 8;
      short8 k0 = *(const short8*)(Kc + q5 * 64 + ch);
      short8 k1 = *(const short8*)(Kc + (32 + q5) * 64 + ch);
      s0 = MFMA32(k0, qf[ks], s0);
      s1 = MFMA32(k1, qf[ks], s1);
    }
    __builtin_amdgcn_s_setprio(0);

    // ---- online softmax, per-lane scalars (lane owns q = q5) ----
    // max3 tree: 32 values in 15 v_max3 + 1 v_max (was 31 v_max)
    float m0 = fmax3(s0[0], s0[1], s0[2]);
    float m1 = fmax3(s0[3], s0[4], s0[5]);
    float m2 = fmax3(s0[6], s0[7], s0[8]);
    float m3 = fmax3(s0[9], s0[10], s0[11]);
    float m4 = fmax3(s0[12], s0[13], s0[14]);
    float m5 = fmax3(s0[15], s1[0], s1[1]);
    float m6 = fmax3(s1[2], s1[3], s1[4]);
    float m7 = fmax3(s1[5], s1[6], s1[7]);
    float m8 = fmax3(s1[8], s1[9], s1[10]);
    float m9 = fmax3(s1[11], s1[12], s1[13]);
    float ma = fmaxf(s1[14], s1[15]);
    float n0 = fmax3(m0, m1, m2);
    float n1 = fmax3(m3, m4, m5);
    float n2 = fmax3(m6, m7, m8);
    float n3 = fmax3(m9, ma, n0);
    float pmax = fmax3(n1, n2, n3);
    pmax = fmaxf(pmax, __shfl_xor(pmax, 32, 64));
    float mraw = pmax * SCALE;

    if (__any(mraw > m_run + 8.f)) {  // T13 defer-max, wave-uniform
      float mn = fmaxf(m_run, mraw);
      float alpha = fexp2(m_run - mn);
#pragma unroll
      for (int i = 0; i < 16; ++i) { o0[i] *= alpha; o1[i] *= alpha; }
      l_run *= alpha;  // per-half partial scales consistently (alpha half-sym)
      m_run = mn;
    }

    float p0[16], p1[16];
    float rs = 0.f;
#pragma unroll
    for (int i = 0; i < 16; ++i) {
      p0[i] = fexp2(fmaf(s0[i], SCALE, -m_run));
      p1[i] = fexp2(fmaf(s1[i], SCALE, -m_run));
      rs += p0[i] + p1[i];
    }
    l_run += rs;  // own-half only; cross-half deferred to after the loop

    // ---- P^T -> PV B-frags in-register (cvt_pk + permlane32_swap) ----
    u32 w0[4][2], w1[4][2];
#pragma unroll
    for (int a = 0; a < 4; ++a) {
      w0[a][0] = cvtpk_bf16(p0[4 * a], p0[4 * a + 1]);
      w0[a][1] = cvtpk_bf16(p0[4 * a + 2], p0[4 * a + 3]);
      w1[a][0] = cvtpk_bf16(p1[4 * a], p1[4 * a + 1]);
      w1[a][1] = cvtpk_bf16(p1[4 * a + 2], p1[4 * a + 3]);
    }
    short8 pb[4];
#pragma unroll
    for (int ks = 0; ks < 4; ++ks) {
      int e = ks & 1;
      u32 x0 = (ks < 2) ? w0[2 * e][0] : w1[2 * e][0];
      u32 y0 = (ks < 2) ? w0[2 * e + 1][0] : w1[2 * e + 1][0];
      u32 x1 = (ks < 2) ? w0[2 * e][1] : w1[2 * e][1];
      u32 y1 = (ks < 2) ? w0[2 * e + 1][1] : w1[2 * e + 1][1];
      asm("v_permlane32_swap_b32 %0, %1" : "+v"(x0), "+v"(y0));
      asm("v_permlane32_swap_b32 %0, %1" : "+v"(x1), "+v"(y1));
      u32x4 tt = {x0, x1, y0, y1};  // words j={0,1},{2,3},{4,5},{6,7}
      pb[ks] = __builtin_bit_cast(short8, tt);
    }

    // ---- O^T += V^T . P^T ----
    const u16* Vc = Vg + cur * 4096;
    __builtin_amdgcn_s_setprio(1);
#pragma unroll
    for (int ks = 0; ks < 4; ++ks) {
      int ch0 = ((ks * 2 + hi) ^ (q5 & 7) ^ ((q5 >> 3) & 7)) * 8;
      int ch1 = ch0 ^ (4 * 8);  // row 32+q5: (d>>3) flips bit 2
      short8 v0 = *(const short8*)(Vc + q5 * 64 + ch0);
      short8 v1 = *(const short8*)(Vc + (32 + q5) * 64 + ch1);
      o0 = MFMA32(v0, pb[ks], o0);
      o1 = MFMA32(v1, pb[ks], o1);
    }
    __builtin_amdgcn_s_setprio(0);

    __syncthreads();  // one barrier per tile: publishes K/V [nxt]
  }
#undef STAGE

  // deferred cross-half l reduction (replaces 16 in-loop shfls)
  l_run += __shfl_xor(l_run, 32, 64);

  // ---- flash-combine of group 0/1 partials through LDS ----
  // overlay (K/V dead; last loop barrier ordered all reads):
  // per gw: M[64] | L[64] | O[32][64]  (2176 floats = 8704B; 4*8704 <= 64KB)
  float* sm = (float*)SM;
  float* base = sm + gw * 2176;
  if (g == 1) {
    base[lane] = m_run;
    base[64 + lane] = l_run;
#pragma unroll
    for (int i = 0; i < 16; ++i) {
      base[128 + i * 64 + lane] = o0[i];
      base[128 + (16 + i) * 64 + lane] = o1[i];
    }
  }
  __syncthreads();
  if (g == 0) {
    float m1 = base[lane], l1 = base[64 + lane];
    float M = fmaxf(m_run, m1);
    float wa = fexp2(m_run - M), wb = fexp2(m1 - M);
    float inv = 1.f / (wa * l_run + wb * l1);
    // epilogue: O^T[d][q], lane q5; d = (reg&3)+8*(reg>>2)+4*hi+32*dt
#pragma unroll
    for (int dt = 0; dt < 2; ++dt)
#pragma unroll
      for (int gq = 0; gq < 4; ++gq) {
        us4 st;
#pragma unroll
        for (int c2 = 0; c2 < 4; ++c2) {
          int i = 4 * gq + c2;
          float mine = (dt == 0) ? o0[i] : o1[i];
          float oth = base[128 + (dt * 16 + i) * 64 + lane];
          st[c2] = f2bf((wa * mine + wb * oth) * inv);
        }
        int col = h * 64 + dt * 32 + 8 * gq + 4 * hi;
        *(us4*)(attn_out + qrow * 1024 + col) = st;
      }
  }
}

// ================= launcher =================
extern "C" void kernel_launch(void* const* d_in, const int* in_sizes, int n_in,
                              void* d_out, int out_size, void* d_ws, size_t ws_size,
                              hipStream_t stream) {
  const float* x = (const float*)d_in[0];
  const float* Wqkv = (const float*)d_in[1];
  const float* Wproj = (const float*)d_in[2];
  const float* bproj = (const float*)d_in[3];
  float* out = (float*)d_out;

  char* ws = (char*)d_ws;
  u16* x_bf     = (u16*)(ws);                 //  8 MB  [4096,1024]
  u16* wqkv_bf  = (u16*)(ws + 8388608);       //  6 MB  [3072,1024]
  u16* wproj_bf = (u16*)(ws + 14680064);      //  2 MB  [1024,1024]
  u16* qk_bf    = (u16*)(ws + 16777216);      // 16 MB  [4096,2048] (Q|K)
  u16* vt_bf    = (u16*)(ws + 33554432);      //  8 MB  [1024,4096] V^T
  u16* attn_bf  = (u16*)(ws + 41943040);      //  8 MB  [4096,1024]

  cvt_all<<<8192, 256, 0, stream>>>(x, x_bf, Wqkv, wqkv_bf, Wproj, wproj_bf);

  fused_qkv_gemm<<<768, 256, 0, stream>>>(x_bf, wqkv_bf, qk_bf, vt_bf);

  attn_kernel<<<512, 512, 0, stream>>>(qk_bf, vt_bf, attn_bf);

  gemm_proj<<<512, 256, 0, stream>>>(attn_bf, wproj_bf, out, bproj,
                                     4096, 1024, 1024);
}

// Round 14
// 115.300 us; speedup vs baseline: 3.4671x; 1.0154x over previous
//
#include <hip/hip_runtime.h>

typedef unsigned short u16;
typedef unsigned int u32;
typedef __attribute__((ext_vector_type(8))) short short8;
typedef __attribute__((ext_vector_type(8))) __bf16 bf16x8;
typedef __attribute__((ext_vector_type(4))) float f32x4;
typedef __attribute__((ext_vector_type(16))) float f32x16;
typedef __attribute__((ext_vector_type(4))) unsigned short us4;
typedef __attribute__((ext_vector_type(4))) unsigned int u32x4;

#define DEVFN static __device__ __forceinline__

DEVFN u16 f2bf(float f) {
  u32 u = __float_as_uint(f);
  return (u16)((u + 0x7fffu + ((u >> 16) & 1u)) >> 16);  // RNE, finite inputs
}

#if __has_builtin(__builtin_amdgcn_exp2f)
DEVFN float fexp2(float x) { return __builtin_amdgcn_exp2f(x); }
#else
DEVFN float fexp2(float x) { return exp2f(x); }
#endif

DEVFN float fmax3(float a, float b, float c) {  // clang fuses to v_max3_f32
  return fmaxf(fmaxf(a, b), c);
}

// ---- MFMA wrappers: tolerant of short8-typed or bf16x8-typed builtins ----
template <typename T>
DEVFN auto mfma16_imp(T a, T b, f32x4 c, int)
    -> decltype(__builtin_amdgcn_mfma_f32_16x16x32_bf16(a, b, c, 0, 0, 0)) {
  return __builtin_amdgcn_mfma_f32_16x16x32_bf16(a, b, c, 0, 0, 0);
}
template <typename T>
DEVFN f32x4 mfma16_imp(T a, T b, f32x4 c, long) {
  return __builtin_amdgcn_mfma_f32_16x16x32_bf16(
      __builtin_bit_cast(bf16x8, a), __builtin_bit_cast(bf16x8, b), c, 0, 0, 0);
}
DEVFN f32x4 MFMA(short8 a, short8 b, f32x4 c) { return mfma16_imp(a, b, c, 0); }

template <typename T>
DEVFN auto mfma32_imp(T a, T b, f32x16 c, int)
    -> decltype(__builtin_amdgcn_mfma_f32_32x32x16_bf16(a, b, c, 0, 0, 0)) {
  return __builtin_amdgcn_mfma_f32_32x32x16_bf16(a, b, c, 0, 0, 0);
}
template <typename T>
DEVFN f32x16 mfma32_imp(T a, T b, f32x16 c, long) {
  return __builtin_amdgcn_mfma_f32_32x32x16_bf16(
      __builtin_bit_cast(bf16x8, a), __builtin_bit_cast(bf16x8, b), c, 0, 0, 0);
}
DEVFN f32x16 MFMA32(short8 a, short8 b, f32x16 c) { return mfma32_imp(a, b, c, 0); }

// ---- async global->LDS: dest = uniform base + lane*16 ----
DEVFN void gload_lds16(const u16* g, u16* l) {
  __builtin_amdgcn_global_load_lds(
      (__attribute__((address_space(1))) void*)g,
      (__attribute__((address_space(3))) void*)l, 16, 0, 0);
}

DEVFN u32 cvtpk_bf16(float lo, float hi) {
  u32 w;
  asm("v_cvt_pk_bf16_f32 %0, %1, %2" : "=v"(w) : "v"(lo), "v"(hi));
  return w;
}

// ================= fused f32 -> bf16 conversion (one launch) =============
__global__ void __launch_bounds__(256) cvt_all(
    const float* __restrict__ x, u16* __restrict__ xo,
    const float* __restrict__ w1, u16* __restrict__ w1o,
    const float* __restrict__ w2, u16* __restrict__ w2o) {
  int bid = blockIdx.x;
  const float* in;
  u16* out;
  int i;
  if (bid < 4096) {
    in = x; out = xo; i = bid * 256 + threadIdx.x;
  } else if (bid < 7168) {
    in = w1; out = w1o; i = (bid - 4096) * 256 + threadIdx.x;
  } else {
    in = w2; out = w2o; i = (bid - 7168) * 256 + threadIdx.x;
  }
  f32x4 v = ((const f32x4*)in)[i];
  us4 o;
  o[0] = f2bf(v[0]); o[1] = f2bf(v[1]); o[2] = f2bf(v[2]); o[3] = f2bf(v[3]);
  ((us4*)out)[i] = o;
}

// ====== GEMM tile body (BK=32): C[bm:+128, bn:+BN] = A @ B^T =============
// Used by the output projection (BN=64 -> 512 blocks, 2/CU).
template <int F32OUT, int BN>
DEVFN void gemm_tile(const u16* __restrict__ A, const u16* __restrict__ Bm,
                     u16* __restrict__ Cbf, float* __restrict__ Cf,
                     const float* __restrict__ bias, int N, int K, int bm,
                     int bn, u16* As, u16* Bs) {
  const int tid = threadIdx.x;
  const int wave = tid >> 6, lane = tid & 63;
  const int wr = (wave >> 1) * 64, wc = (wave & 1) * (BN / 2);
  const int srow = lane >> 2, scol = (lane & 3) * 8;
  const int fr = lane & 15, fk = (lane >> 4) * 8;
  const int NB = BN / 64;  // B-stage iters per wave
  const int NI = BN / 32;  // n-frags per wave

  f32x4 acc[4][NI] = {};

  for (int k0 = 0; k0 < K; k0 += 32) {
    __syncthreads();
#pragma unroll
    for (int t = 0; t < 2; ++t) {
      int rr = (wave * 2 + t) * 16 + srow;
      gload_lds16(A + (size_t)(bm + rr) * K + k0 + scol, As + (wave * 2 + t) * 512);
    }
#pragma unroll
    for (int t = 0; t < NB; ++t) {
      int rr = (wave * NB + t) * 16 + srow;
      gload_lds16(Bm + (size_t)(bn + rr) * K + k0 + scol, Bs + (wave * NB + t) * 512);
    }
    __syncthreads();
    short8 af[4], bf[NI];
#pragma unroll
    for (int i = 0; i < 4; ++i)
      af[i] = *(const short8*)(As + (wr + i * 16 + fr) * 32 + fk);
#pragma unroll
    for (int i = 0; i < NI; ++i)
      bf[i] = *(const short8*)(Bs + (wc + i * 16 + fr) * 32 + fk);
#pragma unroll
    for (int mi = 0; mi < 4; ++mi)
#pragma unroll
      for (int ni = 0; ni < NI; ++ni)
        acc[mi][ni] = MFMA(af[mi], bf[ni], acc[mi][ni]);
  }

  const int orow = (lane >> 4) * 4, ocol = lane & 15;
#pragma unroll
  for (int mi = 0; mi < 4; ++mi)
#pragma unroll
    for (int ni = 0; ni < NI; ++ni)
#pragma unroll
      for (int r = 0; r < 4; ++r) {
        size_t row = (size_t)(bm + wr + mi * 16 + orow + r);
        size_t col = (size_t)(bn + wc + ni * 16 + ocol);
        if (F32OUT)
          Cf[row * N + col] = acc[mi][ni][r] + bias[col];
        else
          Cbf[row * N + col] = f2bf(acc[mi][ni][r]);
      }
}

// ====== output projection: 128x64 tiles, 512 blocks (2/CU) + T1 swizzle ===
__global__ void __launch_bounds__(256) gemm_proj(
    const u16* __restrict__ A, const u16* __restrict__ Bm,
    float* __restrict__ Cf, const float* __restrict__ bias, int M, int N,
    int K) {
  __shared__ u16 As[128 * 32];
  __shared__ u16 Bs[64 * 32];
  const int B = blockIdx.x;
  const int L = (B & 7) * 64 + (B >> 3);
  gemm_tile<1, 64>(A, Bm, nullptr, Cf, bias, N, K, (L >> 4) * 128,
                   (L & 15) * 64, As, Bs);
}

// ====== GEMM tile body, BK=64, 32x32x16 MFMA (R14) ========================
// Same 128x128 tile / staging / XOR swizzle as before; inner math switched
// from 32x MFMA16 to 16x MFMA32 per K-tile (same 16 ds_read_b128).
// Mechanism: 32x32 matrix op is ~15% more FLOP/cycle (m119: 2495 vs 2176 TF)
// and halves MFMA issue count. Fragment layouts identical to the attn
// kernel's MFMA32 usage (verified all session): A-op lane&31=row,
// (lane>>5)*8=k-off; B-op lane&31=col; C/D col=lane&31,
// row=(r&3)+8*(r>>2)+4*(lane>>5). Chunk swizzle math identical to attn's
// K-read: logical chunk (ks*2+hi), physical = logical ^ (row&7).
DEVFN void gemm_tile64(const u16* __restrict__ A, const u16* __restrict__ Bm,
                       u16* __restrict__ C, int N, int K, int bm, int bn,
                       u16* As, u16* Bs) {
  const int tid = threadIdx.x;
  const int wave = tid >> 6, lane = tid & 63;
  const int wr = (wave >> 1) * 64, wc = (wave & 1) * 64;
  const int rowl = lane >> 3;                // row within 8-row group
  const int scol = ((lane & 7) ^ rowl) * 8;  // pre-swizzled src chunk
  const int r5 = lane & 31, hi = lane >> 5;  // 32x32 frag row / k-half

  f32x16 acc[2][2] = {};  // 64 AGPR (unchanged total)

  for (int k0 = 0; k0 < K; k0 += 64) {
    __syncthreads();
#pragma unroll
    for (int t = 0; t < 4; ++t) {
      int gA = wave * 4 + t;  // 16 groups x 8 rows = 128 rows
      int row = gA * 8 + rowl;
      gload_lds16(A + (size_t)(bm + row) * K + k0 + scol, As + gA * 512);
      gload_lds16(Bm + (size_t)(bn + row) * K + k0 + scol, Bs + gA * 512);
    }
    __syncthreads();
#pragma unroll
    for (int ks = 0; ks < 4; ++ks) {  // 4 k-steps of 16
      // logical chunk = ks*2 + hi; rows wr+r5 / wr+32+r5 share (row&7)=r5&7
      int ch = ((ks * 2 + hi) ^ (r5 & 7)) * 8;
      short8 a0 = *(const short8*)(As + (wr + r5) * 64 + ch);
      short8 a1 = *(const short8*)(As + (wr + 32 + r5) * 64 + ch);
      short8 b0 = *(const short8*)(Bs + (wc + r5) * 64 + ch);
      short8 b1 = *(const short8*)(Bs + (wc + 32 + r5) * 64 + ch);
      acc[0][0] = MFMA32(a0, b0, acc[0][0]);
      acc[0][1] = MFMA32(a0, b1, acc[0][1]);
      acc[1][0] = MFMA32(a1, b0, acc[1][0]);
      acc[1][1] = MFMA32(a1, b1, acc[1][1]);
    }
  }

  // C/D layout: col = lane&31, row = (r&3) + 8*(r>>2) + 4*hi (m74/m101)
#pragma unroll
  for (int mi = 0; mi < 2; ++mi)
#pragma unroll
    for (int ni = 0; ni < 2; ++ni)
#pragma unroll
      for (int r = 0; r < 16; ++r) {
        size_t row =
            (size_t)(bm + wr + mi * 32 + (r & 3) + 8 * (r >> 2) + 4 * hi);
        size_t col = (size_t)(bn + wc + ni * 32 + r5);
        C[row * N + col] = f2bf(acc[mi][ni][r]);
      }
}

// ====== fused projection + T1 XCD swizzle =================================
__global__ void __launch_bounds__(256) fused_qkv_gemm(
    const u16* __restrict__ x, const u16* __restrict__ wqkv,
    u16* __restrict__ qk, u16* __restrict__ vt) {
  __shared__ u16 As[128 * 64];
  __shared__ u16 Bs[128 * 64];
  const int B = blockIdx.x;
  const int L = (B & 7) * 96 + (B >> 3);
  if (L < 512) {
    gemm_tile64(x, wqkv, qk, 2048, 1024, (L >> 4) * 128, (L & 15) * 128,
                As, Bs);
  } else {
    int j = L - 512;
    gemm_tile64(wqkv + (size_t)2048 * 1024, x, vt, 4096, 1024, (j & 7) * 128,
                (j >> 3) * 128, As, Bs);
  }
}

// ================= Flash attention v5.1 (R11 verified best: 53.5us) =======
// qk: [4096, 2048] bf16 (Q|K). vT: [1024, 4096] bf16 (vfeat, token).
// 1D grid 512 blocks x 512 thr (8 waves), in-block KV-split x2, double-buf.
// Occupancy NOTE (R12 lesson): live state = 64 VGPR + 64 AGPR = 128 regs in
// the unified file -> HARD cap 4 waves/SIMD (512/128). This config (2 blocks
// x 8 waves/CU) IS the optimum; forcing more via launch_bounds min-waves
// spills catastrophically (R12: WRITE_SIZE 8MB -> 805MB, 400us).
// T1 XCD swizzle (R9: FETCH 69.7->12.3MB). R11 VALU cuts: deferred cross-half
// l-reduction (16 shfls -> 1), v_max3 pmax tree.
// SQ_LDS_BANK_CONFLICT 2.1M = structural b128 2-way (free, m136) — ignore.
__global__ void __launch_bounds__(512) attn_kernel(const u16* __restrict__ qk,
                                                   const u16* __restrict__ vT,
                                                   u16* __restrict__ attn_out) {
  // 64KB flat: K(g,buf) at (g*2+buf)*4096, V(g,buf) at 16384+(g*2+buf)*4096
  __shared__ u16 SM[32768];

  const int tid = threadIdx.x;
  const int wave = tid >> 6, lane = tid & 63;
  const int g = wave >> 2, gw = wave & 3;  // kv-group, wave-in-group
  const int q5 = lane & 31, hi = lane >> 5;

  // ---- T1 XCD-aware decode: qb fastest in L, (h,b) chunked per XCD ----
  const int B = blockIdx.x;                 // 0..511
  const int L = (B & 7) * 64 + (B >> 3);    // bijective swizzle
  const int qb = L & 15, hb = L >> 4;
  const int h = hb & 15, b = hb >> 4;

  const size_t tok0 = (size_t)b * 2048;
  const float SCALE = 0.18033688011112042f;  // 0.125 * log2(e)

  u16* const Kg = SM + g * 2 * 4096;          // + buf*4096
  u16* const Vg = SM + 16384 + g * 2 * 4096;  // + buf*4096
  const int kvoff = g * 1024;

  // Q B-frags: lane q5 holds Q[q][ks*16 + hi*8 + j]
  const size_t qrow = tok0 + qb * 128 + gw * 32 + q5;
  const u16* qp = qk + qrow * 2048 + h * 64 + hi * 8;
  short8 qf[4];
#pragma unroll
  for (int ks = 0; ks < 4; ++ks) qf[ks] = *(const short8*)(qp + ks * 16);

  const u16* kbase = qk + tok0 * 2048 + 1024 + h * 64;  // + kv*2048
  const u16* vtb = vT + (size_t)h * 64 * 4096 + tok0;   // + d*4096 + kv

  // Static per-lane staging geometry (per group: 4 waves cover 8 row-groups)
  const int rowl = lane >> 3;
  const int k_srcoff = ((lane & 7) ^ rowl) * 8;  // K swizzle key = (row&7)

  float m_run = -1e30f, l_run = 0.f;  // l_run: PER-HALF partial (R11)
  f32x16 o0 = {}, o1 = {};

#define STAGE(kv0, buf)                                                        \
  {                                                                            \
    _Pragma("unroll") for (int c = 0; c < 2; ++c) {                            \
      int rw = c * 4 + gw;                                                     \
      int row = rw * 8 + rowl;                                                 \
      gload_lds16(kbase + (size_t)((kv0) + row) * 2048 + k_srcoff,             \
                  Kg + (buf) * 4096 + rw * 512);                               \
      int vso = (((lane & 7) ^ rowl ^ rw) * 8);  /* key = (d&7)^((d>>3)&7) */  \
      gload_lds16(vtb + (size_t)row * 4096 + (kv0) + vso,                      \
                  Vg + (buf) * 4096 + rw * 512);                               \
    }                                                                          \
  }

  STAGE(kvoff, 0);
  __syncthreads();

  for (int t = 0; t < 16; ++t) {
    const int cur = t & 1, nxt = cur ^ 1;
    if (t < 15) STAGE(kvoff + (t + 1) * 64, nxt);  // in flight across compute

    // ---- S^T = K . Q^T : 2 tiles (kv 0-31 / 32-63), 4 k-steps ----
    const u16* Kc = Kg + cur * 4096;
    f32x16 s0 = {}, s1 = {};
    __builtin_amdgcn_s_setprio(1);
#pragma unroll
    for (int ks = 0; ks < 4; ++ks) {
      int ch = ((ks * 2 + hi) ^ (q5 & 7)) * 8;
      short8 k0 = *(const short8*)(Kc + q5 * 64 + ch);
      short8 k1 = *(const short8*)(Kc + (32 + q5) * 64 + ch);
      s0 = MFMA32(k0, qf[ks], s0);
      s1 = MFMA32(k1, qf[ks], s1);
    }
    __builtin_amdgcn_s_setprio(0);

    // ---- online softmax, per-lane scalars (lane owns q = q5) ----
    // max3 tree: 32 values in 15 v_max3 + 1 v_max (was 31 v_max)
    float m0 = fmax3(s0[0], s0[1], s0[2]);
    float m1 = fmax3(s0[3], s0[4], s0[5]);
    float m2 = fmax3(s0[6], s0[7], s0[8]);
    float m3 = fmax3(s0[9], s0[10], s0[11]);
    float m4 = fmax3(s0[12], s0[13], s0[14]);
    float m5 = fmax3(s0[15], s1[0], s1[1]);
    float m6 = fmax3(s1[2], s1[3], s1[4]);
    float m7 = fmax3(s1[5], s1[6], s1[7]);
    float m8 = fmax3(s1[8], s1[9], s1[10]);
    float m9 = fmax3(s1[11], s1[12], s1[13]);
    float ma = fmaxf(s1[14], s1[15]);
    float n0 = fmax3(m0, m1, m2);
    float n1 = fmax3(m3, m4, m5);
    float n2 = fmax3(m6, m7, m8);
    float n3 = fmax3(m9, ma, n0);
    float pmax = fmax3(n1, n2, n3);
    pmax = fmaxf(pmax, __shfl_xor(pmax, 32, 64));
    float mraw = pmax * SCALE;

    if (__any(mraw > m_run + 8.f)) {  // T13 defer-max, wave-uniform
      float mn = fmaxf(m_run, mraw);
      float alpha = fexp2(m_run - mn);
#pragma unroll
      for (int i = 0; i < 16; ++i) { o0[i] *= alpha; o1[i] *= alpha; }
      l_run *= alpha;  // per-half partial scales consistently (alpha half-sym)
      m_run = mn;
    }

    float p0[16], p1[16];
    float rs = 0.f;
#pragma unroll
    for (int i = 0; i < 16; ++i) {
      p0[i] = fexp2(fmaf(s0[i], SCALE, -m_run));
      p1[i] = fexp2(fmaf(s1[i], SCALE, -m_run));
      rs += p0[i] + p1[i];
    }
    l_run += rs;  // own-half only; cross-half deferred to after the loop

    // ---- P^T -> PV B-frags in-register (cvt_pk + permlane32_swap) ----
    u32 w0[4][2], w1[4][2];
#pragma unroll
    for (int a = 0; a < 4; ++a) {
      w0[a][0] = cvtpk_bf16(p0[4 * a], p0[4 * a + 1]);
      w0[a][1] = cvtpk_bf16(p0[4 * a + 2], p0[4 * a + 3]);
      w1[a][0] = cvtpk_bf16(p1[4 * a], p1[4 * a + 1]);
      w1[a][1] = cvtpk_bf16(p1[4 * a + 2], p1[4 * a + 3]);
    }
    short8 pb[4];
#pragma unroll
    for (int ks = 0; ks < 4; ++ks) {
      int e = ks & 1;
      u32 x0 = (ks < 2) ? w0[2 * e][0] : w1[2 * e][0];
      u32 y0 = (ks < 2) ? w0[2 * e + 1][0] : w1[2 * e + 1][0];
      u32 x1 = (ks < 2) ? w0[2 * e][1] : w1[2 * e][1];
      u32 y1 = (ks < 2) ? w0[2 * e + 1][1] : w1[2 * e + 1][1];
      asm("v_permlane32_swap_b32 %0, %1" : "+v"(x0), "+v"(y0));
      asm("v_permlane32_swap_b32 %0, %1" : "+v"(x1), "+v"(y1));
      u32x4 tt = {x0, x1, y0, y1};  // words j={0,1},{2,3},{4,5},{6,7}
      pb[ks] = __builtin_bit_cast(short8, tt);
    }

    // ---- O^T += V^T . P^T ----
    const u16* Vc = Vg + cur * 4096;
    __builtin_amdgcn_s_setprio(1);
#pragma unroll
    for (int ks = 0; ks < 4; ++ks) {
      int ch0 = ((ks * 2 + hi) ^ (q5 & 7) ^ ((q5 >> 3) & 7)) * 8;
      int ch1 = ch0 ^ (4 * 8);  // row 32+q5: (d>>3) flips bit 2
      short8 v0 = *(const short8*)(Vc + q5 * 64 + ch0);
      short8 v1 = *(const short8*)(Vc + (32 + q5) * 64 + ch1);
      o0 = MFMA32(v0, pb[ks], o0);
      o1 = MFMA32(v1, pb[ks], o1);
    }
    __builtin_amdgcn_s_setprio(0);

    __syncthreads();  // one barrier per tile: publishes K/V [nxt]
  }
#undef STAGE

  // deferred cross-half l reduction (replaces 16 in-loop shfls)
  l_run += __shfl_xor(l_run, 32, 64);

  // ---- flash-combine of group 0/1 partials through LDS ----
  // overlay (K/V dead; last loop barrier ordered all reads):
  // per gw: M[64] | L[64] | O[32][64]  (2176 floats = 8704B; 4*8704 <= 64KB)
  float* sm = (float*)SM;
  float* base = sm + gw * 2176;
  if (g == 1) {
    base[lane] = m_run;
    base[64 + lane] = l_run;
#pragma unroll
    for (int i = 0; i < 16; ++i) {
      base[128 + i * 64 + lane] = o0[i];
      base[128 + (16 + i) * 64 + lane] = o1[i];
    }
  }
  __syncthreads();
  if (g == 0) {
    float m1 = base[lane], l1 = base[64 + lane];
    float M = fmaxf(m_run, m1);
    float wa = fexp2(m_run - M), wb = fexp2(m1 - M);
    float inv = 1.f / (wa * l_run + wb * l1);
    // epilogue: O^T[d][q], lane q5; d = (reg&3)+8*(reg>>2)+4*hi+32*dt
#pragma unroll
    for (int dt = 0; dt < 2; ++dt)
#pragma unroll
      for (int gq = 0; gq < 4; ++gq) {
        us4 st;
#pragma unroll
        for (int c2 = 0; c2 < 4; ++c2) {
          int i = 4 * gq + c2;
          float mine = (dt == 0) ? o0[i] : o1[i];
          float oth = base[128 + (dt * 16 + i) * 64 + lane];
          st[c2] = f2bf((wa * mine + wb * oth) * inv);
        }
        int col = h * 64 + dt * 32 + 8 * gq + 4 * hi;
        *(us4*)(attn_out + qrow * 1024 + col) = st;
      }
  }
}

// ================= launcher =================
extern "C" void kernel_launch(void* const* d_in, const int* in_sizes, int n_in,
                              void* d_out, int out_size, void* d_ws, size_t ws_size,
                              hipStream_t stream) {
  const float* x = (const float*)d_in[0];
  const float* Wqkv = (const float*)d_in[1];
  const float* Wproj = (const float*)d_in[2];
  const float* bproj = (const float*)d_in[3];
  float* out = (float*)d_out;

  char* ws = (char*)d_ws;
  u16* x_bf     = (u16*)(ws);                 //  8 MB  [4096,1024]
  u16* wqkv_bf  = (u16*)(ws + 8388608);       //  6 MB  [3072,1024]
  u16* wproj_bf = (u16*)(ws + 14680064);      //  2 MB  [1024,1024]
  u16* qk_bf    = (u16*)(ws + 16777216);      // 16 MB  [4096,2048] (Q|K)
  u16* vt_bf    = (u16*)(ws + 33554432);      //  8 MB  [1024,4096] V^T
  u16* attn_bf  = (u16*)(ws + 41943040);      //  8 MB  [4096,1024]

  cvt_all<<<8192, 256, 0, stream>>>(x, x_bf, Wqkv, wqkv_bf, Wproj, wproj_bf);

  fused_qkv_gemm<<<768, 256, 0, stream>>>(x_bf, wqkv_bf, qk_bf, vt_bf);

  attn_kernel<<<512, 512, 0, stream>>>(qk_bf, vt_bf, attn_bf);

  gemm_proj<<<512, 256, 0, stream>>>(attn_bf, wproj_bf, out, bproj,
                                     4096, 1024, 1024);
}

// Round 15
// 110.643 us; speedup vs baseline: 3.6131x; 1.0421x over previous
//
#include <hip/hip_runtime.h>

typedef unsigned short u16;
typedef unsigned int u32;
typedef __attribute__((ext_vector_type(8))) short short8;
typedef __attribute__((ext_vector_type(8))) __bf16 bf16x8;
typedef __attribute__((ext_vector_type(4))) float f32x4;
typedef __attribute__((ext_vector_type(16))) float f32x16;
typedef __attribute__((ext_vector_type(4))) unsigned short us4;
typedef __attribute__((ext_vector_type(4))) unsigned int u32x4;

#define DEVFN static __device__ __forceinline__

DEVFN u16 f2bf(float f) {
  u32 u = __float_as_uint(f);
  return (u16)((u + 0x7fffu + ((u >> 16) & 1u)) >> 16);  // RNE, finite inputs
}

#if __has_builtin(__builtin_amdgcn_exp2f)
DEVFN float fexp2(float x) { return __builtin_amdgcn_exp2f(x); }
#else
DEVFN float fexp2(float x) { return exp2f(x); }
#endif

DEVFN float fmax3(float a, float b, float c) {  // clang fuses to v_max3_f32
  return fmaxf(fmaxf(a, b), c);
}

// ---- MFMA wrappers: tolerant of short8-typed or bf16x8-typed builtins ----
template <typename T>
DEVFN auto mfma16_imp(T a, T b, f32x4 c, int)
    -> decltype(__builtin_amdgcn_mfma_f32_16x16x32_bf16(a, b, c, 0, 0, 0)) {
  return __builtin_amdgcn_mfma_f32_16x16x32_bf16(a, b, c, 0, 0, 0);
}
template <typename T>
DEVFN f32x4 mfma16_imp(T a, T b, f32x4 c, long) {
  return __builtin_amdgcn_mfma_f32_16x16x32_bf16(
      __builtin_bit_cast(bf16x8, a), __builtin_bit_cast(bf16x8, b), c, 0, 0, 0);
}
DEVFN f32x4 MFMA(short8 a, short8 b, f32x4 c) { return mfma16_imp(a, b, c, 0); }

template <typename T>
DEVFN auto mfma32_imp(T a, T b, f32x16 c, int)
    -> decltype(__builtin_amdgcn_mfma_f32_32x32x16_bf16(a, b, c, 0, 0, 0)) {
  return __builtin_amdgcn_mfma_f32_32x32x16_bf16(a, b, c, 0, 0, 0);
}
template <typename T>
DEVFN f32x16 mfma32_imp(T a, T b, f32x16 c, long) {
  return __builtin_amdgcn_mfma_f32_32x32x16_bf16(
      __builtin_bit_cast(bf16x8, a), __builtin_bit_cast(bf16x8, b), c, 0, 0, 0);
}
DEVFN f32x16 MFMA32(short8 a, short8 b, f32x16 c) { return mfma32_imp(a, b, c, 0); }

// ---- async global->LDS: dest = uniform base + lane*16 ----
DEVFN void gload_lds16(const u16* g, u16* l) {
  __builtin_amdgcn_global_load_lds(
      (__attribute__((address_space(1))) void*)g,
      (__attribute__((address_space(3))) void*)l, 16, 0, 0);
}

DEVFN u32 cvtpk_bf16(float lo, float hi) {
  u32 w;
  asm("v_cvt_pk_bf16_f32 %0, %1, %2" : "=v"(w) : "v"(lo), "v"(hi));
  return w;
}

// ================= fused f32 -> bf16 conversion (one launch) =============
__global__ void __launch_bounds__(256) cvt_all(
    const float* __restrict__ x, u16* __restrict__ xo,
    const float* __restrict__ w1, u16* __restrict__ w1o,
    const float* __restrict__ w2, u16* __restrict__ w2o) {
  int bid = blockIdx.x;
  const float* in;
  u16* out;
  int i;
  if (bid < 4096) {
    in = x; out = xo; i = bid * 256 + threadIdx.x;
  } else if (bid < 7168) {
    in = w1; out = w1o; i = (bid - 4096) * 256 + threadIdx.x;
  } else {
    in = w2; out = w2o; i = (bid - 7168) * 256 + threadIdx.x;
  }
  f32x4 v = ((const f32x4*)in)[i];
  us4 o;
  o[0] = f2bf(v[0]); o[1] = f2bf(v[1]); o[2] = f2bf(v[2]); o[3] = f2bf(v[3]);
  ((us4*)out)[i] = o;
}

// ====== GEMM tile body, BK=64, 32x32x16 MFMA (R14/R15) ====================
// C[bm:+128, bn:+BN] = A[M,K] @ B[N,K]^T, BN in {128, 64}.
// 4 waves; wave owns 64 x BN/2; acc[2][NI] f32x16 (NI = BN/64).
// XOR source-pre-swizzle: stage logical chunk (lane&7)^(lane>>3) at physical
// (lane&7); read physical = logical ^ (row&7) -> <=2-way on ds_read_b128
// (verified: attn K-read, R14 qkv). 32x32 frag layouts m74/m101-verified:
// A/B-op lane&31 = row/col, (lane>>5)*8 = k-offset within 16-step;
// C/D col = lane&31, row = (r&3) + 8*(r>>2) + 4*(lane>>5).
template <int F32OUT, int BN>
DEVFN void gemm_tile64(const u16* __restrict__ A, const u16* __restrict__ Bm,
                       u16* __restrict__ Cbf, float* __restrict__ Cf,
                       const float* __restrict__ bias, int N, int K, int bm,
                       int bn, u16* As, u16* Bs) {
  const int tid = threadIdx.x;
  const int wave = tid >> 6, lane = tid & 63;
  const int wr = (wave >> 1) * 64, wc = (wave & 1) * (BN / 2);
  const int rowl = lane >> 3;                // row within 8-row group
  const int scol = ((lane & 7) ^ rowl) * 8;  // pre-swizzled src chunk
  const int r5 = lane & 31, hi = lane >> 5;  // 32x32 frag row / k-half
  const int NI = BN / 64;                    // 32-col frags per wave
  const int NBG = BN / 32;                   // B-stage groups per wave

  f32x16 acc[2][NI] = {};

  for (int k0 = 0; k0 < K; k0 += 64) {
    __syncthreads();
#pragma unroll
    for (int t = 0; t < 4; ++t) {
      int gA = wave * 4 + t;  // 16 groups x 8 rows = 128 A-rows
      int row = gA * 8 + rowl;
      gload_lds16(A + (size_t)(bm + row) * K + k0 + scol, As + gA * 512);
    }
#pragma unroll
    for (int t = 0; t < NBG; ++t) {
      int gB = wave * NBG + t;  // BN/8 groups = BN B-rows
      int row = gB * 8 + rowl;
      gload_lds16(Bm + (size_t)(bn + row) * K + k0 + scol, Bs + gB * 512);
    }
    __syncthreads();
#pragma unroll
    for (int ks = 0; ks < 4; ++ks) {  // 4 k-steps of 16
      int ch = ((ks * 2 + hi) ^ (r5 & 7)) * 8;
      short8 a0 = *(const short8*)(As + (wr + r5) * 64 + ch);
      short8 a1 = *(const short8*)(As + (wr + 32 + r5) * 64 + ch);
      short8 bfr[NI];
#pragma unroll
      for (int ni = 0; ni < NI; ++ni)
        bfr[ni] = *(const short8*)(Bs + (wc + ni * 32 + r5) * 64 + ch);
#pragma unroll
      for (int ni = 0; ni < NI; ++ni) {
        acc[0][ni] = MFMA32(a0, bfr[ni], acc[0][ni]);
        acc[1][ni] = MFMA32(a1, bfr[ni], acc[1][ni]);
      }
    }
  }

  // C/D layout: col = lane&31, row = (r&3) + 8*(r>>2) + 4*hi (m74/m101)
#pragma unroll
  for (int mi = 0; mi < 2; ++mi)
#pragma unroll
    for (int ni = 0; ni < NI; ++ni)
#pragma unroll
      for (int r = 0; r < 16; ++r) {
        size_t row =
            (size_t)(bm + wr + mi * 32 + (r & 3) + 8 * (r >> 2) + 4 * hi);
        size_t col = (size_t)(bn + wc + ni * 32 + r5);
        if (F32OUT)
          Cf[row * N + col] = acc[mi][ni][r] + bias[col];
        else
          Cbf[row * N + col] = f2bf(acc[mi][ni][r]);
      }
}

// ====== output projection: 128x64 tiles, 512 blocks (2/CU) + T1 swizzle ===
// R15: ported to the BK=64 / MFMA32 tile body (same template as qkv).
__global__ void __launch_bounds__(256) gemm_proj(
    const u16* __restrict__ A, const u16* __restrict__ Bm,
    float* __restrict__ Cf, const float* __restrict__ bias, int M, int N,
    int K) {
  __shared__ u16 As[128 * 64];
  __shared__ u16 Bs[64 * 64];
  const int B = blockIdx.x;
  const int L = (B & 7) * 64 + (B >> 3);
  gemm_tile64<1, 64>(A, Bm, nullptr, Cf, bias, N, K, (L >> 4) * 128,
                     (L & 15) * 64, As, Bs);
}

// ====== fused projection + T1 XCD swizzle =================================
__global__ void __launch_bounds__(256) fused_qkv_gemm(
    const u16* __restrict__ x, const u16* __restrict__ wqkv,
    u16* __restrict__ qk, u16* __restrict__ vt) {
  __shared__ u16 As[128 * 64];
  __shared__ u16 Bs[128 * 64];
  const int B = blockIdx.x;
  const int L = (B & 7) * 96 + (B >> 3);
  if (L < 512) {
    gemm_tile64<0, 128>(x, wqkv, qk, nullptr, nullptr, 2048, 1024,
                        (L >> 4) * 128, (L & 15) * 128, As, Bs);
  } else {
    int j = L - 512;
    gemm_tile64<0, 128>(wqkv + (size_t)2048 * 1024, x, vt, nullptr, nullptr,
                        4096, 1024, (j & 7) * 128, (j >> 3) * 128, As, Bs);
  }
}

// ================= Flash attention v5.1 (R11 verified best: 53.5us) =======
// qk: [4096, 2048] bf16 (Q|K). vT: [1024, 4096] bf16 (vfeat, token).
// 1D grid 512 blocks x 512 thr (8 waves), in-block KV-split x2, double-buf.
// Occupancy NOTE (R12 lesson): live state = 64 VGPR + 64 AGPR = 128 regs in
// the unified file -> HARD cap 4 waves/SIMD (512/128). This config (2 blocks
// x 8 waves/CU) IS the optimum; forcing more via launch_bounds min-waves
// spills catastrophically (R12: WRITE_SIZE 8MB -> 805MB, 400us).
// T1 XCD swizzle (R9: FETCH 69.7->12.3MB). R11 VALU cuts: deferred cross-half
// l-reduction (16 shfls -> 1), v_max3 pmax tree.
// SQ_LDS_BANK_CONFLICT 2.1M = structural b128 2-way (free, m136) — ignore.
__global__ void __launch_bounds__(512) attn_kernel(const u16* __restrict__ qk,
                                                   const u16* __restrict__ vT,
                                                   u16* __restrict__ attn_out) {
  // 64KB flat: K(g,buf) at (g*2+buf)*4096, V(g,buf) at 16384+(g*2+buf)*4096
  __shared__ u16 SM[32768];

  const int tid = threadIdx.x;
  const int wave = tid >> 6, lane = tid & 63;
  const int g = wave >> 2, gw = wave & 3;  // kv-group, wave-in-group
  const int q5 = lane & 31, hi = lane >> 5;

  // ---- T1 XCD-aware decode: qb fastest in L, (h,b) chunked per XCD ----
  const int B = blockIdx.x;                 // 0..511
  const int L = (B & 7) * 64 + (B >> 3);    // bijective swizzle
  const int qb = L & 15, hb = L >> 4;
  const int h = hb & 15, b = hb >> 4;

  const size_t tok0 = (size_t)b * 2048;
  const float SCALE = 0.18033688011112042f;  // 0.125 * log2(e)

  u16* const Kg = SM + g * 2 * 4096;          // + buf*4096
  u16* const Vg = SM + 16384 + g * 2 * 4096;  // + buf*4096
  const int kvoff = g * 1024;

  // Q B-frags: lane q5 holds Q[q][ks*16 + hi*8 + j]
  const size_t qrow = tok0 + qb * 128 + gw * 32 + q5;
  const u16* qp = qk + qrow * 2048 + h * 64 + hi * 8;
  short8 qf[4];
#pragma unroll
  for (int ks = 0; ks < 4; ++ks) qf[ks] = *(const short8*)(qp + ks * 16);

  const u16* kbase = qk + tok0 * 2048 + 1024 + h * 64;  // + kv*2048
  const u16* vtb = vT + (size_t)h * 64 * 4096 + tok0;   // + d*4096 + kv

  // Static per-lane staging geometry (per group: 4 waves cover 8 row-groups)
  const int rowl = lane >> 3;
  const int k_srcoff = ((lane & 7) ^ rowl) * 8;  // K swizzle key = (row&7)

  float m_run = -1e30f, l_run = 0.f;  // l_run: PER-HALF partial (R11)
  f32x16 o0 = {}, o1 = {};

#define STAGE(kv0, buf)                                                        \
  {                                                                            \
    _Pragma("unroll") for (int c = 0; c < 2; ++c) {                            \
      int rw = c * 4 + gw;                                                     \
      int row = rw * 8 + rowl;                                                 \
      gload_lds16(kbase + (size_t)((kv0) + row) * 2048 + k_srcoff,             \
                  Kg + (buf) * 4096 + rw * 512);                               \
      int vso = (((lane & 7) ^ rowl ^ rw) * 8);  /* key = (d&7)^((d>>3)&7) */  \
      gload_lds16(vtb + (size_t)row * 4096 + (kv0) + vso,                      \
                  Vg + (buf) * 4096 + rw * 512);                               \
    }                                                                          \
  }

  STAGE(kvoff, 0);
  __syncthreads();

  for (int t = 0; t < 16; ++t) {
    const int cur = t & 1, nxt = cur ^ 1;
    if (t < 15) STAGE(kvoff + (t + 1) * 64, nxt);  // in flight across compute

    // ---- S^T = K . Q^T : 2 tiles (kv 0-31 / 32-63), 4 k-steps ----
    const u16* Kc = Kg + cur * 4096;
    f32x16 s0 = {}, s1 = {};
    __builtin_amdgcn_s_setprio(1);
#pragma unroll
    for (int ks = 0; ks < 4; ++ks) {
      int ch = ((ks * 2 + hi) ^ (q5 & 7)) * 8;
      short8 k0 = *(const short8*)(Kc + q5 * 64 + ch);
      short8 k1 = *(const short8*)(Kc + (32 + q5) * 64 + ch);
      s0 = MFMA32(k0, qf[ks], s0);
      s1 = MFMA32(k1, qf[ks], s1);
    }
    __builtin_amdgcn_s_setprio(0);

    // ---- online softmax, per-lane scalars (lane owns q = q5) ----
    // max3 tree: 32 values in 15 v_max3 + 1 v_max (was 31 v_max)
    float m0 = fmax3(s0[0], s0[1], s0[2]);
    float m1 = fmax3(s0[3], s0[4], s0[5]);
    float m2 = fmax3(s0[6], s0[7], s0[8]);
    float m3 = fmax3(s0[9], s0[10], s0[11]);
    float m4 = fmax3(s0[12], s0[13], s0[14]);
    float m5 = fmax3(s0[15], s1[0], s1[1]);
    float m6 = fmax3(s1[2], s1[3], s1[4]);
    float m7 = fmax3(s1[5], s1[6], s1[7]);
    float m8 = fmax3(s1[8], s1[9], s1[10]);
    float m9 = fmax3(s1[11], s1[12], s1[13]);
    float ma = fmaxf(s1[14], s1[15]);
    float n0 = fmax3(m0, m1, m2);
    float n1 = fmax3(m3, m4, m5);
    float n2 = fmax3(m6, m7, m8);
    float n3 = fmax3(m9, ma, n0);
    float pmax = fmax3(n1, n2, n3);
    pmax = fmaxf(pmax, __shfl_xor(pmax, 32, 64));
    float mraw = pmax * SCALE;

    if (__any(mraw > m_run + 8.f)) {  // T13 defer-max, wave-uniform
      float mn = fmaxf(m_run, mraw);
      float alpha = fexp2(m_run - mn);
#pragma unroll
      for (int i = 0; i < 16; ++i) { o0[i] *= alpha; o1[i] *= alpha; }
      l_run *= alpha;  // per-half partial scales consistently (alpha half-sym)
      m_run = mn;
    }

    float p0[16], p1[16];
    float rs = 0.f;
#pragma unroll
    for (int i = 0; i < 16; ++i) {
      p0[i] = fexp2(fmaf(s0[i], SCALE, -m_run));
      p1[i] = fexp2(fmaf(s1[i], SCALE, -m_run));
      rs += p0[i] + p1[i];
    }
    l_run += rs;  // own-half only; cross-half deferred to after the loop

    // ---- P^T -> PV B-frags in-register (cvt_pk + permlane32_swap) ----
    u32 w0[4][2], w1[4][2];
#pragma unroll
    for (int a = 0; a < 4; ++a) {
      w0[a][0] = cvtpk_bf16(p0[4 * a], p0[4 * a + 1]);
      w0[a][1] = cvtpk_bf16(p0[4 * a + 2], p0[4 * a + 3]);
      w1[a][0] = cvtpk_bf16(p1[4 * a], p1[4 * a + 1]);
      w1[a][1] = cvtpk_bf16(p1[4 * a + 2], p1[4 * a + 3]);
    }
    short8 pb[4];
#pragma unroll
    for (int ks = 0; ks < 4; ++ks) {
      int e = ks & 1;
      u32 x0 = (ks < 2) ? w0[2 * e][0] : w1[2 * e][0];
      u32 y0 = (ks < 2) ? w0[2 * e + 1][0] : w1[2 * e + 1][0];
      u32 x1 = (ks < 2) ? w0[2 * e][1] : w1[2 * e][1];
      u32 y1 = (ks < 2) ? w0[2 * e + 1][1] : w1[2 * e + 1][1];
      asm("v_permlane32_swap_b32 %0, %1" : "+v"(x0), "+v"(y0));
      asm("v_permlane32_swap_b32 %0, %1" : "+v"(x1), "+v"(y1));
      u32x4 tt = {x0, x1, y0, y1};  // words j={0,1},{2,3},{4,5},{6,7}
      pb[ks] = __builtin_bit_cast(short8, tt);
    }

    // ---- O^T += V^T . P^T ----
    const u16* Vc = Vg + cur * 4096;
    __builtin_amdgcn_s_setprio(1);
#pragma unroll
    for (int ks = 0; ks < 4; ++ks) {
      int ch0 = ((ks * 2 + hi) ^ (q5 & 7) ^ ((q5 >> 3) & 7)) * 8;
      int ch1 = ch0 ^ (4 * 8);  // row 32+q5: (d>>3) flips bit 2
      short8 v0 = *(const short8*)(Vc + q5 * 64 + ch0);
      short8 v1 = *(const short8*)(Vc + (32 + q5) * 64 + ch1);
      o0 = MFMA32(v0, pb[ks], o0);
      o1 = MFMA32(v1, pb[ks], o1);
    }
    __builtin_amdgcn_s_setprio(0);

    __syncthreads();  // one barrier per tile: publishes K/V [nxt]
  }
#undef STAGE

  // deferred cross-half l reduction (replaces 16 in-loop shfls)
  l_run += __shfl_xor(l_run, 32, 64);

  // ---- flash-combine of group 0/1 partials through LDS ----
  // overlay (K/V dead; last loop barrier ordered all reads):
  // per gw: M[64] | L[64] | O[32][64]  (2176 floats = 8704B; 4*8704 <= 64KB)
  float* sm = (float*)SM;
  float* base = sm + gw * 2176;
  if (g == 1) {
    base[lane] = m_run;
    base[64 + lane] = l_run;
#pragma unroll
    for (int i = 0; i < 16; ++i) {
      base[128 + i * 64 + lane] = o0[i];
      base[128 + (16 + i) * 64 + lane] = o1[i];
    }
  }
  __syncthreads();
  if (g == 0) {
    float m1 = base[lane], l1 = base[64 + lane];
    float M = fmaxf(m_run, m1);
    float wa = fexp2(m_run - M), wb = fexp2(m1 - M);
    float inv = 1.f / (wa * l_run + wb * l1);
    // epilogue: O^T[d][q], lane q5; d = (reg&3)+8*(reg>>2)+4*hi+32*dt
#pragma unroll
    for (int dt = 0; dt < 2; ++dt)
#pragma unroll
      for (int gq = 0; gq < 4; ++gq) {
        us4 st;
#pragma unroll
        for (int c2 = 0; c2 < 4; ++c2) {
          int i = 4 * gq + c2;
          float mine = (dt == 0) ? o0[i] : o1[i];
          float oth = base[128 + (dt * 16 + i) * 64 + lane];
          st[c2] = f2bf((wa * mine + wb * oth) * inv);
        }
        int col = h * 64 + dt * 32 + 8 * gq + 4 * hi;
        *(us4*)(attn_out + qrow * 1024 + col) = st;
      }
  }
}

// ================= launcher =================
extern "C" void kernel_launch(void* const* d_in, const int* in_sizes, int n_in,
                              void* d_out, int out_size, void* d_ws, size_t ws_size,
                              hipStream_t stream) {
  const float* x = (const float*)d_in[0];
  const float* Wqkv = (const float*)d_in[1];
  const float* Wproj = (const float*)d_in[2];
  const float* bproj = (const float*)d_in[3];
  float* out = (float*)d_out;

  char* ws = (char*)d_ws;
  u16* x_bf     = (u16*)(ws);                 //  8 MB  [4096,1024]
  u16* wqkv_bf  = (u16*)(ws + 8388608);       //  6 MB  [3072,1024]
  u16* wproj_bf = (u16*)(ws + 14680064);      //  2 MB  [1024,1024]
  u16* qk_bf    = (u16*)(ws + 16777216);      // 16 MB  [4096,2048] (Q|K)
  u16* vt_bf    = (u16*)(ws + 33554432);      //  8 MB  [1024,4096] V^T
  u16* attn_bf  = (u16*)(ws + 41943040);      //  8 MB  [4096,1024]

  cvt_all<<<8192, 256, 0, stream>>>(x, x_bf, Wqkv, wqkv_bf, Wproj, wproj_bf);

  fused_qkv_gemm<<<768, 256, 0, stream>>>(x_bf, wqkv_bf, qk_bf, vt_bf);

  attn_kernel<<<512, 512, 0, stream>>>(qk_bf, vt_bf, attn_bf);

  gemm_proj<<<512, 256, 0, stream>>>(attn_bf, wproj_bf, out, bproj,
                                     4096, 1024, 1024);
}